// Round 11
// baseline (48.532 us; speedup 1.0000x reference)
//
#include <hip/hip_runtime.h>
#include <math.h>

// Problem constants (match reference setup_inputs)
#define Hc 96
#define Wc 96
#define Bc 2
#define Cc 256            // channels
#define HWc (Hc * Wc)     // 9216
#define NKc 25            // 5x5 neighborhood
#define NPIX (Bc * HWc)   // 18432
#define NSLOT 32          // spread accumulation slots

// Workspace byte offsets
#define OFF_ACC 0                        // NSLOT*2 floats (heavy loss per class)
#define OFF_CNT 256                      // 2 floats: contributing count per class
#define OFF_MIS 264                      // 2 floats: mispredicted count per class
#define OFF_HC 272                       // 1 uint: heavy worklist count
#define OFF_DONE 276                     // 1 uint: heavy arrival counter
#define HDR_FLOATS 80                    // first 320 B zeroed by transpose blk 0
#define OFF_NRM2 320                     // 2*NPIX floats: per-half sum of squares
#define OFF_META (OFF_NRM2 + 2 * NPIX * 4)  // NPIX bytes: label | pred<<1
#define OFF_WL (OFF_META + NPIX)         // NPIX uint4 worklist
#define OFF_FT (OFF_WL + NPIX * 16)      // NPIX*Cc bf16 featT (9.4 MB)

__device__ __forceinline__ float wave_reduce_sum(float v) {
#pragma unroll
  for (int off = 32; off > 0; off >>= 1) v += __shfl_xor(v, off);
  return v;
}

// neighbor k -> flat pixel offset (compile-time per unrolled k)
#define NOFF(k) (((k) / 5 - 2) * Wc + ((k) % 5 - 2))

// f32 -> bf16 (RNE), packed pair; bf16 -> f32
__device__ __forceinline__ unsigned f2bf_pack(float lo, float hi) {
  unsigned a = __float_as_uint(lo), b = __float_as_uint(hi);
  a = (a + 0x7FFFu + ((a >> 16) & 1u)) >> 16;
  b = (b + 0x7FFFu + ((b >> 16) & 1u)) >> 16;
  return a | (b << 16);
}
__device__ __forceinline__ float bf2f(unsigned short u) {
  return __uint_as_float(((unsigned)u) << 16);
}

// ---------------------------------------------------------------
// 1) Transpose er_input [B,C,HW] -> featT [B,HW,C] in bf16.  Grid z
//    splits channels into two 128-halves; per-half f32 sum-of-squares
//    finishes in-block (plain store).  Half 0 writes packed meta;
//    block (0,0,0) zeroes the 320-byte accumulator header.
// ---------------------------------------------------------------
__global__ __launch_bounds__(256) void transpose_kernel(
    const float* __restrict__ in, const float* __restrict__ seg_logit,
    const int* __restrict__ seg_label, unsigned* __restrict__ outb,
    float* __restrict__ nrm2h, unsigned char* __restrict__ meta,
    float* __restrict__ hdr) {
  __shared__ float tile[64][33];
  __shared__ float part[8][32];
  const int bx = blockIdx.x;    // 0..287 pixel tile
  const int b = blockIdx.y;     // batch
  const int half = blockIdx.z;  // channel half (0: 0..127, 1: 128..255)
  const int tx = threadIdx.x;   // 0..31
  const int ty = threadIdx.y;   // 0..7
  const float* src = in + (size_t)b * Cc * HWc;
  const int p0 = bx * 32;

  if (bx == 0 && b == 0 && half == 0) {
    const int t = ty * 32 + tx;
    if (t < HDR_FLOATS) hdr[t] = 0.f;
  }

  float psum = 0.f;
  for (int s = 0; s < 2; ++s) {
    const int c0 = half * 128 + s * 64;
#pragma unroll
    for (int i = 0; i < 8; i++)
      tile[ty + i * 8][tx] = src[(size_t)(c0 + ty + i * 8) * HWc + p0 + tx];
    __syncthreads();
#pragma unroll
    for (int i = 0; i < 4; i++) {
      const int px = ty + i * 8;  // 0..31
      const unsigned pk = f2bf_pack(tile[2 * tx][px], tile[2 * tx + 1][px]);
      outb[(size_t)(b * HWc + p0 + px) * (Cc / 2) + (c0 / 2) + tx] = pk;
    }
#pragma unroll
    for (int j = 0; j < 8; j++) {
      const float v = tile[ty * 8 + j][tx];
      psum += v * v;
    }
    __syncthreads();
  }
  part[ty][tx] = psum;
  __syncthreads();
  if (ty == 0) {
    float t = 0.f;
#pragma unroll
    for (int j = 0; j < 8; j++) t += part[j][tx];
    const int hw = p0 + tx;
    const int gi = b * HWc + hw;
    nrm2h[half * NPIX + gi] = t;
    if (half == 0) {
      const float l0 = seg_logit[(size_t)(b * 2 + 0) * HWc + hw];
      const float l1 = seg_logit[(size_t)(b * 2 + 1) * HWc + hw];
      const int pr = (l1 > l0) ? 1 : 0;
      meta[gi] = (unsigned char)((seg_label[gi] & 1) | (pr << 1));
    }
  }
}

// ---------------------------------------------------------------
// 2) Classify: 1 thread/pixel.  Counts contributing/mispredicted
//    pixels per class; compacts heavy pixels into GLOBAL worklist.
// ---------------------------------------------------------------
__global__ __launch_bounds__(256) void classify_kernel(
    const unsigned char* __restrict__ meta, const int* __restrict__ gtb,
    const float* __restrict__ nrm2h, float* __restrict__ cnt,
    float* __restrict__ mis, unsigned int* __restrict__ heavyCount,
    uint4* __restrict__ worklist) {
  __shared__ unsigned int s_cnt[4];  // cnt0, cnt1, mis0, mis1
  if (threadIdx.x < 4) s_cnt[threadIdx.x] = 0;
  __syncthreads();
  const int tid = blockIdx.x * 256 + threadIdx.x;  // < NPIX
  bool heavy = false;
  int c = 0;
  unsigned mNow = 0, mNeg = 0;
  float a_norm = 0.f;
  {
    const int hw = tid % HWc;
    const int h = hw / Wc, w = hw % Wc;
    int g = gtb[tid];
    if (g == 255) g = 0;
    if (g) {  // boundary pixel
      const int m0 = meta[tid];
      c = m0 & 1;
      const int pc = (m0 >> 1) & 1;
      const int oc = 1 - c;
      int count = 0;
#pragma unroll
      for (int k = 0; k < NKc; k++) {
        const int di = k / 5 - 2, dj = k % 5 - 2;
        const int hh = h + di, ww = w + dj;
        const bool inb = (hh >= 0) && (hh < Hc) && (ww >= 0) && (ww < Wc);
        const int mv = inb ? (int)meta[tid + di * Wc + dj] : 0;  // zero-pad
        const int lb = mv & 1, pr = (mv >> 1) & 1;
        count += (lb == c);
        if (inb) {
          if (lb == c && pr == c) mNow |= 1u << k;
          if (lb == oc && pr == oc) mNeg |= 1u << k;
        }
        // OOB with oc==0 has w_neg=2 but feat=0,norm=0 -> neg_cos=0, identical
        // to the zero-logit bucket: safe to leave both bits unset.  OOB mNow
        // bit unset also safe: feat=0 adds nothing to the positive sum.
      }
      count -= 1;        // exclude center (always label==c)
      if (count >= 1) {  // contributing pixel
        atomicAdd(&s_cnt[c], 1u);
        if (pc == c) {
          heavy = true;
          a_norm = sqrtf(nrm2h[tid] + nrm2h[NPIX + tid]);
        } else {
          atomicAdd(&s_cnt[2 + c], 1u);  // constant log(26) loss
        }
      }
    }
  }
  const unsigned long long m = __ballot(heavy);
  const int lane = threadIdx.x & 63;
  if (m) {
    unsigned int base = 0;
    if (lane == 0) base = atomicAdd(heavyCount, (unsigned)__popcll(m));
    base = __shfl(base, 0);
    if (heavy) {
      const unsigned idx = base + (unsigned)__popcll(m & ((1ull << lane) - 1ull));
      worklist[idx] = make_uint4((unsigned)tid | ((unsigned)c << 16), mNow, mNeg,
                                 __float_as_uint(a_norm));
    }
  }
  __syncthreads();
  if (threadIdx.x < 2) {
    if (s_cnt[threadIdx.x]) atomicAdd(&cnt[threadIdx.x], (float)s_cnt[threadIdx.x]);
    if (s_cnt[2 + threadIdx.x]) atomicAdd(&mis[threadIdx.x], (float)s_cnt[2 + threadIdx.x]);
  }
}

// ---------------------------------------------------------------
// 3) Heavy + finalize.  One wave per worklist entry (grid-stride).
//    Branchless compute: one pinned load batch, 25 dot partials,
//    ILP butterfly reduction of ALL 25 dots at once (no serial
//    reduce chains), per-lane masked softmax.  ad falls out of the
//    reduced dots (a.pv = (sum_now - D_center)/25).  Last-arriving
//    block reduces the slots and writes out[0].
// ---------------------------------------------------------------
__global__ __launch_bounds__(256) void heavy_kernel(
    const ushort4* __restrict__ ftb, const float* __restrict__ nrm2h,
    const unsigned int* __restrict__ heavyCount,
    const uint4* __restrict__ worklist, float* __restrict__ accum,
    unsigned int* __restrict__ doneCnt, const float* __restrict__ cnt,
    const float* __restrict__ mis, float* __restrict__ out) {
  __shared__ float s_loss[2];
  __shared__ unsigned s_last;
  if (threadIdx.x < 2) s_loss[threadIdx.x] = 0.f;
  __syncthreads();
  const int lane = threadIdx.x & 63;
  const int wv = threadIdx.x >> 6;
  const unsigned nH = *heavyCount;
  const unsigned nw = gridDim.x * 4;
  float lacc0 = 0.f, lacc1 = 0.f;
  for (unsigned i = blockIdx.x * 4 + wv; i < nH; i += nw) {
    const uint4 e = worklist[i];
    const int wid = e.x & 0xffff;
    const int c = (e.x >> 16) & 1;
    const unsigned mNow = e.y, mNeg = e.z;
    const unsigned mAny = mNow | mNeg;
    const float a_norm = __uint_as_float(e.w);

    // ---- one pinned load batch ----
    float nk2a = 0.f, nk2b = 0.f;
    if (lane < NKc && ((mNeg >> lane) & 1u)) {
      const int nb = wid + (lane / 5 - 2) * Wc + (lane % 5 - 2);
      nk2a = nrm2h[nb];
      nk2b = nrm2h[NPIX + nb];
    }
    const ushort4 a4 = ftb[(size_t)wid * 64 + lane];
    ushort4 f4[NKc];
#pragma unroll
    for (int k = 0; k < NKc; k++) {
      f4[k] = make_ushort4(0, 0, 0, 0);
      if ((mAny >> k) & 1u)  // wave-uniform; no use inside branch
        f4[k] = ftb[(size_t)(wid + NOFF(k)) * 64 + lane];
    }
    asm volatile("" ::: "memory");  // pin loads above compute

    const float ax = bf2f(a4.x), ay = bf2f(a4.y), az = bf2f(a4.z), aw = bf2f(a4.w);
    const float nkv = sqrtf(nk2a + nk2b);

    // ---- per-lane dot partials + masked positive sum (branchless) ----
    float dpart[NKc];
    float4 pos = make_float4(0.f, 0.f, 0.f, 0.f);
#pragma unroll
    for (int k = 0; k < NKc; k++) {
      const float fx = bf2f(f4[k].x), fy = bf2f(f4[k].y);
      const float fz = bf2f(f4[k].z), fw = bf2f(f4[k].w);
      dpart[k] = ax * fx + ay * fy + az * fz + aw * fw;
      const float wN = (float)((mNow >> k) & 1u);
      pos.x = fmaf(fx, wN, pos.x);
      pos.y = fmaf(fy, wN, pos.y);
      pos.z = fmaf(fz, wN, pos.z);
      pos.w = fmaf(fw, wN, pos.w);
    }

    // ---- butterfly-reduce ALL 25 dots at once (ILP, no serial chains) ----
#pragma unroll
    for (int s = 32; s > 0; s >>= 1) {
#pragma unroll
      for (int k = 0; k < NKc; k++) dpart[k] += __shfl_xor(dpart[k], s);
    }
    // every lane now holds all 25 full dots (uniform)

    // positive cosine: a.pv = (sum_{k in mNow} D_k - D_center)/25
    float sNow = 0.f;
#pragma unroll
    for (int k = 0; k < NKc; k++)
      sNow += (float)((mNow >> k) & 1u) * dpart[k];
    const float adN = (sNow - dpart[12]) * (1.0f / 25.0f);
    // p2 needs the vector: one remaining reduction
    float4 pv;
    pv.x = (pos.x - ax) * (1.0f / 25.0f);
    pv.y = (pos.y - ay) * (1.0f / 25.0f);
    pv.z = (pos.z - az) * (1.0f / 25.0f);
    pv.w = (pos.w - aw) * (1.0f / 25.0f);
    const float p2 = wave_reduce_sum(pv.x * pv.x + pv.y * pv.y + pv.z * pv.z + pv.w * pv.w);
    const float x0 = (adN / (a_norm * sqrtf(p2) + 1e-8f)) * 10.0f;

    // ---- negatives: branchless masked softmax (all values uniform) ----
    const float an2 = a_norm * 2.0f;
    float xm[NKc];
#pragma unroll
    for (int k = 0; k < NKc; k++) {
      const float nk = __shfl(nkv, k);
      const float xk = (dpart[k] * 20.0f) / (an2 * nk + 1e-8f);
      xm[k] = ((mNeg >> k) & 1u) ? xk : -1e30f;
    }
    float mx = fmaxf(x0, 0.f);  // >=1 zero-logit always present (center)
#pragma unroll
    for (int k = 0; k < NKc; k++) mx = fmaxf(mx, xm[k]);
    float ssum = __expf(x0 - mx) + (float)(NKc - __popc(mNeg)) * __expf(-mx);
#pragma unroll
    for (int k = 0; k < NKc; k++) ssum += __expf(xm[k] - mx);  // masked -> 0
    const float loss = mx + __logf(ssum) - x0;
    if (lane == 0) {
      if (c == 0) lacc0 += loss; else lacc1 += loss;
    }
  }
  if (lane == 0) {
    if (lacc0 != 0.f) atomicAdd(&s_loss[0], lacc0);
    if (lacc1 != 0.f) atomicAdd(&s_loss[1], lacc1);
  }
  __syncthreads();
  if (threadIdx.x < 2) {
    const float v = s_loss[threadIdx.x];
    if (v != 0.f) atomicAdd(&accum[(blockIdx.x & (NSLOT - 1)) * 2 + threadIdx.x], v);
  }
  // ---- finalize: last-arriving block (atomic-only ordering; the
  // __syncthreads drains this block's vmem so slot atomics are at the
  // device coherence point before doneCnt is bumped) ----
  __syncthreads();
  if (threadIdx.x == 0)
    s_last = (atomicAdd(doneCnt, 1u) == (unsigned)(gridDim.x - 1)) ? 1u : 0u;
  __syncthreads();
  if (s_last && threadIdx.x < NSLOT * 2) {
    const float v = atomicAdd(&accum[threadIdx.x], 0.0f);  // coherent read
    float v0 = (threadIdx.x & 1) ? 0.f : v;
    float v1 = (threadIdx.x & 1) ? v : 0.f;
    v0 = wave_reduce_sum(v0);
    v1 = wave_reduce_sum(v1);
    if (threadIdx.x == 0) {
      const float LOG26 = logf(26.0f);
      out[0] = (v0 + LOG26 * mis[0]) / fmaxf(cnt[0], 1.0f) +
               (v1 + LOG26 * mis[1]) / fmaxf(cnt[1], 1.0f);
    }
  }
}

extern "C" void kernel_launch(void* const* d_in, const int* in_sizes, int n_in,
                              void* d_out, int out_size, void* d_ws, size_t ws_size,
                              hipStream_t stream) {
  const float* er = (const float*)d_in[0];         // [B,C,H,W]
  const float* seg_logit = (const float*)d_in[1];  // [B,2,H,W]
  const int* seg_label = (const int*)d_in[2];      // [B,H,W]
  const int* gtb = (const int*)d_in[3];            // [B,H,W]
  float* out = (float*)d_out;

  char* ws = (char*)d_ws;
  float* hdr = (float*)ws;  // first 320 B: accum/cnt/mis/heavyCount/doneCnt
  float* accum = (float*)(ws + OFF_ACC);
  float* cnt = (float*)(ws + OFF_CNT);
  float* mis = (float*)(ws + OFF_MIS);
  unsigned int* heavyCount = (unsigned int*)(ws + OFF_HC);
  unsigned int* doneCnt = (unsigned int*)(ws + OFF_DONE);
  float* nrm2h = (float*)(ws + OFF_NRM2);
  unsigned char* meta = (unsigned char*)(ws + OFF_META);
  uint4* worklist = (uint4*)(ws + OFF_WL);
  unsigned* featTb = (unsigned*)(ws + OFF_FT);

  dim3 tb(32, 8, 1);
  dim3 tg(HWc / 32, Bc, 2);  // 288 x 2 x 2 (z = channel half)
  transpose_kernel<<<tg, tb, 0, stream>>>(er, seg_logit, seg_label, featTb,
                                          nrm2h, meta, hdr);

  classify_kernel<<<NPIX / 256, 256, 0, stream>>>(meta, gtb, nrm2h, cnt, mis,
                                                  heavyCount, worklist);

  heavy_kernel<<<1152, 256, 0, stream>>>((const ushort4*)featTb, nrm2h,
                                         heavyCount, worklist, accum, doneCnt,
                                         cnt, mis, out);
}

// Round 12
// 45.526 us; speedup vs baseline: 1.0660x; 1.0660x over previous
//
#include <hip/hip_runtime.h>
#include <math.h>

// Problem constants (match reference setup_inputs)
#define Hc 96
#define Wc 96
#define Bc 2
#define Cc 256            // channels
#define HWc (Hc * Wc)     // 9216
#define NKc 25            // 5x5 neighborhood
#define NPIX (Bc * HWc)   // 18432
#define NSLOT 32          // spread accumulation slots

// Workspace byte offsets
#define OFF_ACC 0                        // NSLOT*2 floats (heavy loss per class)
#define OFF_CNT 256                      // 2 floats: contributing count per class
#define OFF_MIS 264                      // 2 floats: mispredicted count per class
#define OFF_HC 272                       // 1 uint: heavy worklist count
#define OFF_DONE 276                     // 1 uint: heavy arrival counter
#define HDR_FLOATS 80                    // first 320 B zeroed by transpose blk 0
#define OFF_NRM2 320                     // 2*NPIX floats: per-half sum of squares
#define OFF_META (OFF_NRM2 + 2 * NPIX * 4)  // NPIX bytes: label | pred<<1
#define OFF_WL (OFF_META + NPIX)         // NPIX uint4 worklist
#define OFF_FT (OFF_WL + NPIX * 16)      // NPIX*Cc bf16 featT (9.4 MB)

__device__ __forceinline__ float wave_reduce_sum(float v) {
#pragma unroll
  for (int off = 32; off > 0; off >>= 1) v += __shfl_xor(v, off);
  return v;
}

// neighbor k -> flat pixel offset (compile-time per unrolled k)
#define NOFF(k) (((k) / 5 - 2) * Wc + ((k) % 5 - 2))

// f32 -> bf16 (RNE), packed pair; bf16 -> f32
__device__ __forceinline__ unsigned f2bf_pack(float lo, float hi) {
  unsigned a = __float_as_uint(lo), b = __float_as_uint(hi);
  a = (a + 0x7FFFu + ((a >> 16) & 1u)) >> 16;
  b = (b + 0x7FFFu + ((b >> 16) & 1u)) >> 16;
  return a | (b << 16);
}
__device__ __forceinline__ float bf2f(unsigned short u) {
  return __uint_as_float(((unsigned)u) << 16);
}

// ---------------------------------------------------------------
// 1) Transpose er_input [B,C,HW] -> featT [B,HW,C] in bf16.  Grid z
//    splits channels into two 128-halves; per-half f32 sum-of-squares
//    finishes in-block (plain store).  Half 0 writes packed meta;
//    block (0,0,0) zeroes the 320-byte accumulator header.
// ---------------------------------------------------------------
__global__ __launch_bounds__(256) void transpose_kernel(
    const float* __restrict__ in, const float* __restrict__ seg_logit,
    const int* __restrict__ seg_label, unsigned* __restrict__ outb,
    float* __restrict__ nrm2h, unsigned char* __restrict__ meta,
    float* __restrict__ hdr) {
  __shared__ float tile[64][33];
  __shared__ float part[8][32];
  const int bx = blockIdx.x;    // 0..287 pixel tile
  const int b = blockIdx.y;     // batch
  const int half = blockIdx.z;  // channel half (0: 0..127, 1: 128..255)
  const int tx = threadIdx.x;   // 0..31
  const int ty = threadIdx.y;   // 0..7
  const float* src = in + (size_t)b * Cc * HWc;
  const int p0 = bx * 32;

  if (bx == 0 && b == 0 && half == 0) {
    const int t = ty * 32 + tx;
    if (t < HDR_FLOATS) hdr[t] = 0.f;
  }

  float psum = 0.f;
  for (int s = 0; s < 2; ++s) {
    const int c0 = half * 128 + s * 64;
#pragma unroll
    for (int i = 0; i < 8; i++)
      tile[ty + i * 8][tx] = src[(size_t)(c0 + ty + i * 8) * HWc + p0 + tx];
    __syncthreads();
#pragma unroll
    for (int i = 0; i < 4; i++) {
      const int px = ty + i * 8;  // 0..31
      const unsigned pk = f2bf_pack(tile[2 * tx][px], tile[2 * tx + 1][px]);
      outb[(size_t)(b * HWc + p0 + px) * (Cc / 2) + (c0 / 2) + tx] = pk;
    }
#pragma unroll
    for (int j = 0; j < 8; j++) {
      const float v = tile[ty * 8 + j][tx];
      psum += v * v;
    }
    __syncthreads();
  }
  part[ty][tx] = psum;
  __syncthreads();
  if (ty == 0) {
    float t = 0.f;
#pragma unroll
    for (int j = 0; j < 8; j++) t += part[j][tx];
    const int hw = p0 + tx;
    const int gi = b * HWc + hw;
    nrm2h[half * NPIX + gi] = t;
    if (half == 0) {
      const float l0 = seg_logit[(size_t)(b * 2 + 0) * HWc + hw];
      const float l1 = seg_logit[(size_t)(b * 2 + 1) * HWc + hw];
      const int pr = (l1 > l0) ? 1 : 0;
      meta[gi] = (unsigned char)((seg_label[gi] & 1) | (pr << 1));
    }
  }
}

// ---------------------------------------------------------------
// 2) Classify: 1 thread/pixel.  Counts contributing/mispredicted
//    pixels per class; compacts heavy pixels into GLOBAL worklist.
// ---------------------------------------------------------------
__global__ __launch_bounds__(256) void classify_kernel(
    const unsigned char* __restrict__ meta, const int* __restrict__ gtb,
    const float* __restrict__ nrm2h, float* __restrict__ cnt,
    float* __restrict__ mis, unsigned int* __restrict__ heavyCount,
    uint4* __restrict__ worklist) {
  __shared__ unsigned int s_cnt[4];  // cnt0, cnt1, mis0, mis1
  if (threadIdx.x < 4) s_cnt[threadIdx.x] = 0;
  __syncthreads();
  const int tid = blockIdx.x * 256 + threadIdx.x;  // < NPIX
  bool heavy = false;
  int c = 0;
  unsigned mNow = 0, mNeg = 0;
  float a_norm = 0.f;
  {
    const int hw = tid % HWc;
    const int h = hw / Wc, w = hw % Wc;
    int g = gtb[tid];
    if (g == 255) g = 0;
    if (g) {  // boundary pixel
      const int m0 = meta[tid];
      c = m0 & 1;
      const int pc = (m0 >> 1) & 1;
      const int oc = 1 - c;
      int count = 0;
#pragma unroll
      for (int k = 0; k < NKc; k++) {
        const int di = k / 5 - 2, dj = k % 5 - 2;
        const int hh = h + di, ww = w + dj;
        const bool inb = (hh >= 0) && (hh < Hc) && (ww >= 0) && (ww < Wc);
        const int mv = inb ? (int)meta[tid + di * Wc + dj] : 0;  // zero-pad
        const int lb = mv & 1, pr = (mv >> 1) & 1;
        count += (lb == c);
        if (inb) {
          if (lb == c && pr == c) mNow |= 1u << k;
          if (lb == oc && pr == oc) mNeg |= 1u << k;
        }
        // OOB with oc==0 has w_neg=2 but feat=0,norm=0 -> neg_cos=0, identical
        // to the zero-logit bucket: safe to leave both bits unset.  OOB mNow
        // bit unset also safe: feat=0 adds nothing to the positive sum.
      }
      count -= 1;        // exclude center (always label==c)
      if (count >= 1) {  // contributing pixel
        atomicAdd(&s_cnt[c], 1u);
        if (pc == c) {
          heavy = true;
          a_norm = sqrtf(nrm2h[tid] + nrm2h[NPIX + tid]);
        } else {
          atomicAdd(&s_cnt[2 + c], 1u);  // constant log(26) loss
        }
      }
    }
  }
  const unsigned long long m = __ballot(heavy);
  const int lane = threadIdx.x & 63;
  if (m) {
    unsigned int base = 0;
    if (lane == 0) base = atomicAdd(heavyCount, (unsigned)__popcll(m));
    base = __shfl(base, 0);
    if (heavy) {
      const unsigned idx = base + (unsigned)__popcll(m & ((1ull << lane) - 1ull));
      worklist[idx] = make_uint4((unsigned)tid | ((unsigned)c << 16), mNow, mNeg,
                                 __float_as_uint(a_norm));
    }
  }
  __syncthreads();
  if (threadIdx.x < 2) {
    if (s_cnt[threadIdx.x]) atomicAdd(&cnt[threadIdx.x], (float)s_cnt[threadIdx.x]);
    if (s_cnt[2 + threadIdx.x]) atomicAdd(&mis[threadIdx.x], (float)s_cnt[2 + threadIdx.x]);
  }
}

// ---------------------------------------------------------------
// 3) Heavy + finalize.  One wave per worklist entry (grid-stride).
//    __launch_bounds__(256,2): VGPR budget 128 so the WHOLE load
//    batch (f4[25] = 50 VGPRs) stays live & in flight.  Loads are
//    branchless: unset-mask neighbors load from wid itself (the
//    anchor's hot line -> no extra HBM traffic); their values are
//    provably unused (wN masks positives, mNeg gates negatives).
//    Online softmax for negatives (round-10 form, best measured).
// ---------------------------------------------------------------
__global__ __launch_bounds__(256, 2) void heavy_kernel(
    const ushort4* __restrict__ ftb, const float* __restrict__ nrm2h,
    const unsigned int* __restrict__ heavyCount,
    const uint4* __restrict__ worklist, float* __restrict__ accum,
    unsigned int* __restrict__ doneCnt, const float* __restrict__ cnt,
    const float* __restrict__ mis, float* __restrict__ out) {
  __shared__ float s_loss[2];
  __shared__ unsigned s_last;
  if (threadIdx.x < 2) s_loss[threadIdx.x] = 0.f;
  __syncthreads();
  const int lane = threadIdx.x & 63;
  const int wv = threadIdx.x >> 6;
  const unsigned nH = *heavyCount;
  const unsigned nw = gridDim.x * 4;
  float lacc0 = 0.f, lacc1 = 0.f;
  for (unsigned i = blockIdx.x * 4 + wv; i < nH; i += nw) {
    const uint4 e = worklist[i];
    const int wid = e.x & 0xffff;
    const int c = (e.x >> 16) & 1;
    const unsigned mNow = e.y, mNeg = e.z;
    const unsigned mAny = mNow | mNeg;
    const float a_norm = __uint_as_float(e.w);

    // ---- branchless clamped-offset load batch (all in flight) ----
    const int dlt = (lane / 5 - 2) * Wc + (lane % 5 - 2);
    const int nbn = (lane < NKc && ((mNeg >> lane) & 1u)) ? wid + dlt : wid;
    const float nk2a = nrm2h[nbn];
    const float nk2b = nrm2h[NPIX + nbn];
    const ushort4 a4 = ftb[(size_t)wid * 64 + lane];
    ushort4 f4[NKc];
#pragma unroll
    for (int k = 0; k < NKc; k++) {
      const int off = ((mAny >> k) & 1u) ? wid + NOFF(k) : wid;
      f4[k] = ftb[(size_t)off * 64 + lane];
    }
    asm volatile("" ::: "memory");  // pin loads above compute

    const float ax = bf2f(a4.x), ay = bf2f(a4.y), az = bf2f(a4.z), aw = bf2f(a4.w);
    const float nkv = sqrtf(nk2a + nk2b);

    // ---- positives: mNow-masked sum (branchless) ----
    float4 pos = make_float4(0.f, 0.f, 0.f, 0.f);
#pragma unroll
    for (int k = 0; k < NKc; k++) {
      const float wN = (float)((mNow >> k) & 1u);
      pos.x = fmaf(bf2f(f4[k].x), wN, pos.x);
      pos.y = fmaf(bf2f(f4[k].y), wN, pos.y);
      pos.z = fmaf(bf2f(f4[k].z), wN, pos.z);
      pos.w = fmaf(bf2f(f4[k].w), wN, pos.w);
    }
    float4 pv;
    pv.x = (pos.x - ax) * (1.0f / 25.0f);
    pv.y = (pos.y - ay) * (1.0f / 25.0f);
    pv.z = (pos.z - az) * (1.0f / 25.0f);
    pv.w = (pos.w - aw) * (1.0f / 25.0f);
    const float p2 = wave_reduce_sum(pv.x * pv.x + pv.y * pv.y + pv.z * pv.z + pv.w * pv.w);
    const float ad = wave_reduce_sum(ax * pv.x + ay * pv.y + az * pv.z + aw * pv.w);
    const float x0 = (ad / (a_norm * sqrtf(p2) + 1e-8f)) * 10.0f;

    // ---- negatives: online softmax (each dot reduced & consumed) ----
    float mx = fmaxf(x0, 0.f);  // >=1 zero-logit always present (center)
    float ssum = __expf(x0 - mx) + (float)(NKc - __popc(mNeg)) * __expf(-mx);
#pragma unroll
    for (int k = 0; k < NKc; k++) {
      if ((mNeg >> k) & 1u) {  // wave-uniform, sparse
        const float d = wave_reduce_sum(ax * bf2f(f4[k].x) + ay * bf2f(f4[k].y) +
                                        az * bf2f(f4[k].z) + aw * bf2f(f4[k].w));
        const float nk = __shfl(nkv, k);
        const float x = ((d * 2.0f) / (a_norm * nk * 2.0f + 1e-8f)) * 10.0f;
        if (x > mx) {  // wave-uniform (x uniform after reduce)
          ssum = ssum * __expf(mx - x) + 1.0f;
          mx = x;
        } else {
          ssum += __expf(x - mx);
        }
      }
    }
    const float loss = mx + __logf(ssum) - x0;
    if (lane == 0) {
      if (c == 0) lacc0 += loss; else lacc1 += loss;
    }
  }
  if (lane == 0) {
    if (lacc0 != 0.f) atomicAdd(&s_loss[0], lacc0);
    if (lacc1 != 0.f) atomicAdd(&s_loss[1], lacc1);
  }
  __syncthreads();
  if (threadIdx.x < 2) {
    const float v = s_loss[threadIdx.x];
    if (v != 0.f) atomicAdd(&accum[(blockIdx.x & (NSLOT - 1)) * 2 + threadIdx.x], v);
  }
  // ---- finalize: last-arriving block (atomic-only ordering; the
  // __syncthreads drains this block's vmem so slot atomics are at the
  // device coherence point before doneCnt is bumped) ----
  __syncthreads();
  if (threadIdx.x == 0)
    s_last = (atomicAdd(doneCnt, 1u) == (unsigned)(gridDim.x - 1)) ? 1u : 0u;
  __syncthreads();
  if (s_last && threadIdx.x < NSLOT * 2) {
    const float v = atomicAdd(&accum[threadIdx.x], 0.0f);  // coherent read
    float v0 = (threadIdx.x & 1) ? 0.f : v;
    float v1 = (threadIdx.x & 1) ? v : 0.f;
    v0 = wave_reduce_sum(v0);
    v1 = wave_reduce_sum(v1);
    if (threadIdx.x == 0) {
      const float LOG26 = logf(26.0f);
      out[0] = (v0 + LOG26 * mis[0]) / fmaxf(cnt[0], 1.0f) +
               (v1 + LOG26 * mis[1]) / fmaxf(cnt[1], 1.0f);
    }
  }
}

extern "C" void kernel_launch(void* const* d_in, const int* in_sizes, int n_in,
                              void* d_out, int out_size, void* d_ws, size_t ws_size,
                              hipStream_t stream) {
  const float* er = (const float*)d_in[0];         // [B,C,H,W]
  const float* seg_logit = (const float*)d_in[1];  // [B,2,H,W]
  const int* seg_label = (const int*)d_in[2];      // [B,H,W]
  const int* gtb = (const int*)d_in[3];            // [B,H,W]
  float* out = (float*)d_out;

  char* ws = (char*)d_ws;
  float* hdr = (float*)ws;  // first 320 B: accum/cnt/mis/heavyCount/doneCnt
  float* accum = (float*)(ws + OFF_ACC);
  float* cnt = (float*)(ws + OFF_CNT);
  float* mis = (float*)(ws + OFF_MIS);
  unsigned int* heavyCount = (unsigned int*)(ws + OFF_HC);
  unsigned int* doneCnt = (unsigned int*)(ws + OFF_DONE);
  float* nrm2h = (float*)(ws + OFF_NRM2);
  unsigned char* meta = (unsigned char*)(ws + OFF_META);
  uint4* worklist = (uint4*)(ws + OFF_WL);
  unsigned* featTb = (unsigned*)(ws + OFF_FT);

  dim3 tb(32, 8, 1);
  dim3 tg(HWc / 32, Bc, 2);  // 288 x 2 x 2 (z = channel half)
  transpose_kernel<<<tg, tb, 0, stream>>>(er, seg_logit, seg_label, featTb,
                                          nrm2h, meta, hdr);

  classify_kernel<<<NPIX / 256, 256, 0, stream>>>(meta, gtb, nrm2h, cnt, mis,
                                                  heavyCount, worklist);

  heavy_kernel<<<1152, 256, 0, stream>>>((const ushort4*)featTb, nrm2h,
                                         heavyCount, worklist, accum, doneCnt,
                                         cnt, mis, out);
}

// Round 13
// 43.242 us; speedup vs baseline: 1.1223x; 1.0528x over previous
//
#include <hip/hip_runtime.h>
#include <math.h>

// Problem constants (match reference setup_inputs)
#define Hc 96
#define Wc 96
#define Bc 2
#define Cc 256            // channels
#define HWc (Hc * Wc)     // 9216
#define NKc 25            // 5x5 neighborhood
#define NPIX (Bc * HWc)   // 18432
#define NSLOT 32          // spread accumulation slots
#define NBLK 576          // half0 blocks (= NPIX/32)

// Workspace byte offsets
#define OFF_ACC 0          // NSLOT*2 floats (heavy loss per class)
#define OFF_DONE 256       // 1 uint: heavy arrival counter
#define OFF_CNTB 512       // NBLK packed uints: cnt0|cnt1<<8|mis0<<16|mis1<<24
#define OFF_NRM2 4096      // 2*NPIX floats: per-half sum of squares
#define OFF_WL 151552      // NPIX uint4: {flags, mNow, mNeg, 0} (slot = pixel)
#define OFF_FT 446464      // NPIX*Cc bf16 featT (9.4 MB)

__device__ __forceinline__ float wave_reduce_sum(float v) {
#pragma unroll
  for (int off = 32; off > 0; off >>= 1) v += __shfl_xor(v, off);
  return v;
}

// neighbor k -> flat pixel offset (compile-time per unrolled k)
#define NOFF(k) (((k) / 5 - 2) * Wc + ((k) % 5 - 2))

// f32 -> bf16 (RNE), packed pair; bf16 -> f32
__device__ __forceinline__ unsigned f2bf_pack(float lo, float hi) {
  unsigned a = __float_as_uint(lo), b = __float_as_uint(hi);
  a = (a + 0x7FFFu + ((a >> 16) & 1u)) >> 16;
  b = (b + 0x7FFFu + ((b >> 16) & 1u)) >> 16;
  return a | (b << 16);
}
__device__ __forceinline__ float bf2f(unsigned short u) {
  return __uint_as_float(((unsigned)u) << 16);
}

// ---------------------------------------------------------------
// 1) Fused transpose + classify.  Transpose er_input -> bf16 featT
//    with per-half sum-of-squares (plain store).  half0 blocks ALSO
//    classify their 32 pixels straight from raw inputs (label /
//    argmax(logits) recomputed per neighbor via lanes 0..24 +
//    ballots -> padded worklist slot per pixel, byte-packed per-
//    block counts (plain stores, no atomics, no pre-zeroing).
//    Block (0,0,0) zeroes kernel B's 320-byte header.
// ---------------------------------------------------------------
__global__ __launch_bounds__(256) void transclass_kernel(
    const float* __restrict__ in, const float* __restrict__ seg_logit,
    const int* __restrict__ seg_label, const int* __restrict__ gtb,
    unsigned* __restrict__ outb, float* __restrict__ nrm2h,
    uint4* __restrict__ wl, unsigned* __restrict__ cntBlk,
    float* __restrict__ hdr) {
  __shared__ float tile[64][33];
  __shared__ float part[8][32];
  __shared__ unsigned s_ccnt[4];
  const int bx = blockIdx.x;    // 0..287 pixel tile
  const int b = blockIdx.y;     // batch
  const int half = blockIdx.z;  // channel half
  const int tx = threadIdx.x;   // 0..31
  const int ty = threadIdx.y;   // 0..7
  const int flat = ty * 32 + tx;
  const float* src = in + (size_t)b * Cc * HWc;
  const int p0 = bx * 32;

  if (bx == 0 && b == 0 && half == 0 && flat < 80) hdr[flat] = 0.f;

  // ---- transpose + norms ----
  float psum = 0.f;
  for (int s = 0; s < 2; ++s) {
    const int c0 = half * 128 + s * 64;
#pragma unroll
    for (int i = 0; i < 8; i++)
      tile[ty + i * 8][tx] = src[(size_t)(c0 + ty + i * 8) * HWc + p0 + tx];
    __syncthreads();
#pragma unroll
    for (int i = 0; i < 4; i++) {
      const int px = ty + i * 8;  // 0..31
      const unsigned pk = f2bf_pack(tile[2 * tx][px], tile[2 * tx + 1][px]);
      outb[(size_t)(b * HWc + p0 + px) * (Cc / 2) + (c0 / 2) + tx] = pk;
    }
#pragma unroll
    for (int j = 0; j < 8; j++) {
      const float v = tile[ty * 8 + j][tx];
      psum += v * v;
    }
    __syncthreads();
  }
  part[ty][tx] = psum;
  __syncthreads();
  if (ty == 0) {
    float t = 0.f;
#pragma unroll
    for (int j = 0; j < 8; j++) t += part[j][tx];
    nrm2h[half * NPIX + b * HWc + p0 + tx] = t;
  }

  // ---- classify phase (half0 blocks only; independent of transpose) ----
  if (half == 0) {
    const int lane = flat & 63;
    const int wv = flat >> 6;  // 0..3, each wave handles 8 pixels
    unsigned wsum = 0;
    for (int px = 0; px < 8; ++px) {
      const int hw = p0 + wv * 8 + px;
      const int tid = b * HWc + hw;
      const int h = hw / Wc, w = hw - h * Wc;
      int g = gtb[tid];
      if (g == 255) g = 0;
      int lb = 0, pr = 0;
      bool inb = false;
      if (lane < NKc) {
        const int di = lane / 5 - 2, dj = lane % 5 - 2;
        const int hh = h + di, ww = w + dj;
        inb = (hh >= 0) && (hh < Hc) && (ww >= 0) && (ww < Wc);
        if (inb) {
          const int d = di * Wc + dj;
          lb = seg_label[tid + d];
          const float l0 = seg_logit[(size_t)(b * 2 + 0) * HWc + hw + d];
          const float l1 = seg_logit[(size_t)(b * 2 + 1) * HWc + hw + d];
          pr = (l1 > l0) ? 1 : 0;
        }
      }
      const int c = __shfl(lb, 12);   // center label (lane 12 in-bounds)
      const int pc = __shfl(pr, 12);  // center pred
      const int count =
          __popcll(__ballot(lane < NKc && lb == c)) - 1;  // zero-pad counts c==0
      const bool valid = (g != 0) && (count >= 1);
      const unsigned mNow =
          (unsigned)__ballot(lane < NKc && inb && lb == c && pr == c);
      const unsigned mNeg =
          (unsigned)__ballot(lane < NKc && inb && lb == (1 - c) && pr == (1 - c));
      // OOB with oc==0 has w_neg=2 but feat=0,norm=0 -> neg_cos=0, identical
      // to the zero-logit bucket: bits safely left unset.
      const bool hv = valid && (pc == c);
      if (lane == 0)
        wl[tid] = make_uint4(hv ? (1u | ((unsigned)c << 1)) : 0u, mNow, mNeg, 0u);
      wsum += valid ? ((1u << (8 * c)) + ((pc != c) ? (1u << (16 + 8 * c)) : 0u))
                    : 0u;
    }
    if (lane == 0) s_ccnt[wv] = wsum;
    __syncthreads();
    if (flat == 0)
      cntBlk[b * 288 + bx] = s_ccnt[0] + s_ccnt[1] + s_ccnt[2] + s_ccnt[3];
  }
}

// ---------------------------------------------------------------
// 2) Heavy + finalize.  Grid-stride over ALL NPIX padded slots
//    (stride 4608 decorrelates boundary clusters -> balanced).
//    Branchless clamped-offset load batch (r12 form), online
//    softmax.  Last-arriving block reduces loss slots + packed
//    per-block counts and writes out[0].
// ---------------------------------------------------------------
__global__ __launch_bounds__(256, 2) void heavy_kernel(
    const ushort4* __restrict__ ftb, const float* __restrict__ nrm2h,
    const uint4* __restrict__ wl, float* __restrict__ accum,
    unsigned int* __restrict__ doneCnt, const unsigned* __restrict__ cntBlk,
    float* __restrict__ out) {
  __shared__ float s_loss[2];
  __shared__ unsigned s_last;
  if (threadIdx.x < 2) s_loss[threadIdx.x] = 0.f;
  __syncthreads();
  const int lane = threadIdx.x & 63;
  const int wv = threadIdx.x >> 6;
  const unsigned nw = gridDim.x * 4;  // 4608
  float lacc0 = 0.f, lacc1 = 0.f;
  for (unsigned i = blockIdx.x * 4 + wv; i < NPIX; i += nw) {
    const uint4 e = wl[i];
    if (!(e.x & 1u)) continue;  // not heavy (wave-uniform)
    const int wid = (int)i;
    const int c = (e.x >> 1) & 1;
    const unsigned mNow = e.y, mNeg = e.z;
    const unsigned mAny = mNow | mNeg;

    // ---- branchless clamped-offset load batch (all in flight) ----
    const float a_norm = sqrtf(nrm2h[wid] + nrm2h[NPIX + wid]);
    const int dlt = (lane / 5 - 2) * Wc + (lane % 5 - 2);
    const int nbn = (lane < NKc && ((mNeg >> lane) & 1u)) ? wid + dlt : wid;
    const float nk2a = nrm2h[nbn];
    const float nk2b = nrm2h[NPIX + nbn];
    const ushort4 a4 = ftb[(size_t)wid * 64 + lane];
    ushort4 f4[NKc];
#pragma unroll
    for (int k = 0; k < NKc; k++) {
      const int off = ((mAny >> k) & 1u) ? wid + NOFF(k) : wid;
      f4[k] = ftb[(size_t)off * 64 + lane];
    }
    asm volatile("" ::: "memory");  // pin loads above compute

    const float ax = bf2f(a4.x), ay = bf2f(a4.y), az = bf2f(a4.z), aw = bf2f(a4.w);
    const float nkv = sqrtf(nk2a + nk2b);

    // ---- positives: mNow-masked sum (branchless) ----
    float4 pos = make_float4(0.f, 0.f, 0.f, 0.f);
#pragma unroll
    for (int k = 0; k < NKc; k++) {
      const float wN = (float)((mNow >> k) & 1u);
      pos.x = fmaf(bf2f(f4[k].x), wN, pos.x);
      pos.y = fmaf(bf2f(f4[k].y), wN, pos.y);
      pos.z = fmaf(bf2f(f4[k].z), wN, pos.z);
      pos.w = fmaf(bf2f(f4[k].w), wN, pos.w);
    }
    float4 pv;
    pv.x = (pos.x - ax) * (1.0f / 25.0f);
    pv.y = (pos.y - ay) * (1.0f / 25.0f);
    pv.z = (pos.z - az) * (1.0f / 25.0f);
    pv.w = (pos.w - aw) * (1.0f / 25.0f);
    const float p2 = wave_reduce_sum(pv.x * pv.x + pv.y * pv.y + pv.z * pv.z + pv.w * pv.w);
    const float ad = wave_reduce_sum(ax * pv.x + ay * pv.y + az * pv.z + aw * pv.w);
    const float x0 = (ad / (a_norm * sqrtf(p2) + 1e-8f)) * 10.0f;

    // ---- negatives: online softmax (each dot reduced & consumed) ----
    float mx = fmaxf(x0, 0.f);  // >=1 zero-logit always present (center)
    float ssum = __expf(x0 - mx) + (float)(NKc - __popc(mNeg)) * __expf(-mx);
#pragma unroll
    for (int k = 0; k < NKc; k++) {
      if ((mNeg >> k) & 1u) {  // wave-uniform, sparse
        const float d = wave_reduce_sum(ax * bf2f(f4[k].x) + ay * bf2f(f4[k].y) +
                                        az * bf2f(f4[k].z) + aw * bf2f(f4[k].w));
        const float nk = __shfl(nkv, k);
        const float x = ((d * 2.0f) / (a_norm * nk * 2.0f + 1e-8f)) * 10.0f;
        if (x > mx) {  // wave-uniform (x uniform after reduce)
          ssum = ssum * __expf(mx - x) + 1.0f;
          mx = x;
        } else {
          ssum += __expf(x - mx);
        }
      }
    }
    const float loss = mx + __logf(ssum) - x0;
    if (lane == 0) {
      if (c == 0) lacc0 += loss; else lacc1 += loss;
    }
  }
  if (lane == 0) {
    if (lacc0 != 0.f) atomicAdd(&s_loss[0], lacc0);
    if (lacc1 != 0.f) atomicAdd(&s_loss[1], lacc1);
  }
  __syncthreads();
  if (threadIdx.x < 2) {
    const float v = s_loss[threadIdx.x];
    if (v != 0.f) atomicAdd(&accum[(blockIdx.x & (NSLOT - 1)) * 2 + threadIdx.x], v);
  }
  // ---- finalize: last-arriving block (atomic-only ordering; the
  // __syncthreads drains this block's vmem so slot atomics are at the
  // device coherence point before doneCnt is bumped) ----
  __syncthreads();
  if (threadIdx.x == 0)
    s_last = (atomicAdd(doneCnt, 1u) == (unsigned)(gridDim.x - 1)) ? 1u : 0u;
  __syncthreads();
  if (s_last && threadIdx.x < 64) {
    const int t = threadIdx.x;
    const float v = atomicAdd(&accum[t], 0.0f);  // coherent read
    float l0 = (t & 1) ? 0.f : v;
    float l1 = (t & 1) ? v : 0.f;
    // per-block packed counts: 576 = 64 x 9
    unsigned pc0 = 0, pc1 = 0, pm0 = 0, pm1 = 0;
#pragma unroll
    for (int j = 0; j < 9; j++) {
      const unsigned u = cntBlk[t * 9 + j];
      pc0 += u & 0xFFu;
      pc1 += (u >> 8) & 0xFFu;
      pm0 += (u >> 16) & 0xFFu;
      pm1 += (u >> 24) & 0xFFu;
    }
    l0 = wave_reduce_sum(l0);
    l1 = wave_reduce_sum(l1);
    const float c0 = wave_reduce_sum((float)pc0);
    const float c1 = wave_reduce_sum((float)pc1);
    const float m0 = wave_reduce_sum((float)pm0);
    const float m1 = wave_reduce_sum((float)pm1);
    if (t == 0) {
      const float LOG26 = logf(26.0f);
      out[0] = (l0 + LOG26 * m0) / fmaxf(c0, 1.0f) +
               (l1 + LOG26 * m1) / fmaxf(c1, 1.0f);
    }
  }
}

extern "C" void kernel_launch(void* const* d_in, const int* in_sizes, int n_in,
                              void* d_out, int out_size, void* d_ws, size_t ws_size,
                              hipStream_t stream) {
  const float* er = (const float*)d_in[0];         // [B,C,H,W]
  const float* seg_logit = (const float*)d_in[1];  // [B,2,H,W]
  const int* seg_label = (const int*)d_in[2];      // [B,H,W]
  const int* gtb = (const int*)d_in[3];            // [B,H,W]
  float* out = (float*)d_out;

  char* ws = (char*)d_ws;
  float* hdr = (float*)ws;  // first 320 B: accum + doneCnt
  float* accum = (float*)(ws + OFF_ACC);
  unsigned int* doneCnt = (unsigned int*)(ws + OFF_DONE);
  unsigned* cntBlk = (unsigned*)(ws + OFF_CNTB);
  float* nrm2h = (float*)(ws + OFF_NRM2);
  uint4* wl = (uint4*)(ws + OFF_WL);
  unsigned* featTb = (unsigned*)(ws + OFF_FT);

  dim3 tb(32, 8, 1);
  dim3 tg(HWc / 32, Bc, 2);  // 288 x 2 x 2 (z = channel half)
  transclass_kernel<<<tg, tb, 0, stream>>>(er, seg_logit, seg_label, gtb,
                                           featTb, nrm2h, wl, cntBlk, hdr);

  heavy_kernel<<<1152, 256, 0, stream>>>((const ushort4*)featTb, nrm2h, wl,
                                         accum, doneCnt, cntBlk, out);
}